// Round 8
// baseline (3854.142 us; speedup 1.0000x reference)
//
#include <hip/hip_runtime.h>
#include <hip/hip_bf16.h>

#define SEQT 2000
#define NB   2048
#define H1   51
#define MROW 4            // batch rows per block
#define NBLK (NB / MROW)  // 512 blocks
#define PADR 40           // shorts per staged row (80 B, 16B-aligned)
#define TSTR (16 * PADR)  // shorts per K-tile (16 rows)

typedef float f32x4 __attribute__((ext_vector_type(4)));
typedef short s16x8 __attribute__((ext_vector_type(8)));

__device__ __forceinline__ short f2bf(float f) { __hip_bfloat16 b(f); return *(short*)&b; }
__device__ __forceinline__ float bf2f(short s) { __hip_bfloat16 b; *(short*)&b = s; return (float)b; }
__device__ __forceinline__ float rbf(float f) { return bf2f(f2bf(f)); }
__device__ __forceinline__ float sigf(float x) { return 1.f / (1.f + __expf(-x)); }
__device__ __forceinline__ float tanhfast(float x) { return 1.f - 2.f / (__expf(2.f * x) + 1.f); }

// K-map (K=160, 5 tiles of 32):
//   col 2u / 2u+1 (u<51): h_hi/h_lo  x  Whh_hi[n][u]
//   col 102+u     (u<51): h_hi       x  Whh_lo[n][u]
//   153: x_hi*Wih_hi | 154: x_lo*Wih_hi | 155: x_hi*Wih_lo
//   156: 1*b_hi | 157: 1*b_lo | 158,159: 0
// N-ordering: n' = u*4 + g  (g = i,f,g,o), 13 tiles of 16 cover u=0..51.
// MFMA: A-operand = W rows (n'), B-operand = h (cols = m).
// C/D: col(lane&15)=m, row(quad*4+reg)=n' -> one lane holds all 4 gates of
// (u = nt*4+quad, m) in its 4 acc regs => lane-local epilogue, 1 barrier/ts.

__global__ void __launch_bounds__(256)
__attribute__((amdgpu_waves_per_eu(2)))
lstm_fused_kernel(const float* __restrict__ input,
                  const float* __restrict__ W_ih1,
                  const float* __restrict__ W_hh1,
                  const float* __restrict__ b_ih1,
                  const float* __restrict__ b_hh1,
                  const float* __restrict__ W_ih3,
                  const float* __restrict__ W_hh3,
                  const float* __restrict__ b_ih3,
                  const float* __restrict__ b_hh3,
                  float* __restrict__ out) {
    const int t = threadIdx.x;
    const int w = t >> 6;        // wave 0..3
    const int lane = t & 63;
    const int iloc = lane & 15, kq = lane >> 4;
    const int r0 = blockIdx.x * MROW;

    __shared__ short Hst[2][5 * TSTR];   // h/x staging, ts-parity dbuf
    __shared__ float C1s[2][4 * 52];
    __shared__ float Obuf[2][4 * 64];

    // ---- W fragments (A-operand) in registers ----
    // wave w owns tiles {w, w+4, w+8, w+12<13}; NT = 4 for w==0 else 3
    const int NT = (w == 0) ? 4 : 3;
    s16x8 Wfr[4][5];
#pragma unroll
    for (int i2 = 0; i2 < 4; ++i2) {
        if (i2 >= NT) break;
        const int np = (w + 4 * i2) * 16 + iloc;   // n' row
        const int u = np >> 2, g = np & 3;
        const int n = g * H1 + u;                  // original gate row
#pragma unroll
        for (int kt = 0; kt < 5; ++kt) {
            s16x8 bf;
#pragma unroll
            for (int jj = 0; jj < 8; ++jj) {
                const int k = kt * 32 + kq * 8 + jj;
                float v = 0.f;
                if (u < H1) {
                    if (k < 102) {
                        v = rbf(W_hh1[n * H1 + (k >> 1)]);
                    } else if (k < 153) {
                        const float wv = W_hh1[n * H1 + (k - 102)];
                        v = wv - rbf(wv);
                    } else if (k == 153 || k == 154) {
                        v = rbf(W_ih1[n]);
                    } else if (k == 155) {
                        const float wv = W_ih1[n];
                        v = wv - rbf(wv);
                    } else if (k == 156) {
                        v = rbf(b_ih1[n] + b_hh1[n]);
                    } else if (k == 157) {
                        const float bv = b_ih1[n] + b_hh1[n];
                        v = bv - rbf(bv);
                    }
                }
                bf[jj] = f2bf(v);
            }
            Wfr[i2][kt] = bf;
        }
    }

    // ---- z/LSTM3 weights (wave 3) ----
    float w3[13];
#pragma unroll
    for (int ii = 0; ii < 13; ++ii) w3[ii] = 0.f;
    if (w == 3) {
        const int g = (lane >> 2) & 3, q = lane & 3;
#pragma unroll
        for (int ii = 0; ii < 13; ++ii) {
            const int u = q * 13 + ii;
            w3[ii] = (u < H1) ? W_ih3[g * H1 + u] : 0.f;
        }
    }
    const float whh3_0 = W_hh3[0], whh3_1 = W_hh3[1];
    const float whh3_2 = W_hh3[2], whh3_3 = W_hh3[3];
    const float b3_0 = b_ih3[0] + b_hh3[0];
    const float b3_1 = b_ih3[1] + b_hh3[1];
    const float b3_2 = b_ih3[2] + b_hh3[2];
    const float b3_3 = b_ih3[3] + b_hh3[3];

    // ---- LDS init ----
    for (int idx = t; idx < 2 * 5 * TSTR; idx += 256)
        ((short*)Hst)[idx] = 0;
    if (t < 4) {
        const int m = t;
#pragma unroll
        for (int p = 0; p < 2; ++p) {
            Hst[p][4 * TSTR + m * PADR + 28] = (short)0x3F80;  // col156: 1.0
            Hst[p][4 * TSTR + m * PADR + 29] = (short)0x3F80;  // col157: 1.0
            C1s[p][m * 52 + 51] = 0.f;
        }
        const float x0 = input[(size_t)(r0 + m) * SEQT];
        const short xh = f2bf(x0), xl = f2bf(x0 - bf2f(xh));
        Hst[1][4 * TSTR + m * PADR + 25] = xh;   // window0 reads parity 1
        Hst[1][4 * TSTR + m * PADR + 26] = xl;
        Hst[1][4 * TSTR + m * PADR + 27] = xh;
    }
    float xreg = 0.f;
    if (w == 2 && iloc == 4)    // x-writer lanes: m = kq
        xreg = input[(size_t)(r0 + kq) * SEQT + 1];
    float c1st[4] = {0.f, 0.f, 0.f, 0.f};   // c1 per owned tile (u=nt*4+kq, m=iloc)
    float h3 = 0.f, c3 = 0.f;               // LSTM3 state (wave 3)

    for (int ts = 0; ts <= SEQT; ++ts) {
        __syncthreads();

        // ---- coalesced output dump of finished 64-chunk ----
        if (ts >= 65 && (ts & 63) == 1) {
            const int c = (ts >> 6) - 1;    // chunk 0..30
            out[(size_t)(r0 + (t >> 6)) * SEQT + c * 64 + (t & 63)] =
                Obuf[c & 1][(t >> 6) * 64 + (t & 63)];
        }

        const int rb = (ts + 1) & 1, wb = ts & 1;

        if (ts < SEQT) {
            // ---- h-frags (B-operand): col m = iloc, only 4 real ----
            s16x8 hf[5];
            if (iloc < MROW) {
                const int hbase = iloc * PADR + kq * 8;
#pragma unroll
                for (int kt = 0; kt < 5; ++kt)
                    hf[kt] = *(const s16x8*)&Hst[rb][kt * TSTR + hbase];
            } else {
#pragma unroll
                for (int kt = 0; kt < 5; ++kt)
                    hf[kt] = (s16x8){0, 0, 0, 0, 0, 0, 0, 0};
            }

            // ---- MFMA + lane-local epilogue per owned tile ----
#pragma unroll
            for (int i2 = 0; i2 < 4; ++i2) {
                if (i2 >= NT) break;
                f32x4 acc = (f32x4){0.f, 0.f, 0.f, 0.f};
#pragma unroll
                for (int kt = 0; kt < 5; ++kt)
                    acc = __builtin_amdgcn_mfma_f32_16x16x32_bf16(
                        Wfr[i2][kt], hf[kt], acc, 0, 0, 0);
                if (iloc < MROW) {
                    const int u = (w + 4 * i2) * 4 + kq;  // unit
                    const int m = iloc;
                    float c1 = c1st[i2];
                    c1 = sigf(acc[1]) * c1 + sigf(acc[0]) * tanhfast(acc[2]);
                    c1st[i2] = c1;
                    const float h1 = sigf(acc[3]) * tanhfast(c1);
                    if (u < H1) {
                        const short hh = f2bf(h1), hl = f2bf(h1 - bf2f(hh));
                        const int c0 = 2 * u;
                        *(unsigned*)&Hst[wb][(c0 >> 5) * TSTR + m * PADR + (c0 & 31)] =
                            (unsigned)(unsigned short)hh |
                            ((unsigned)(unsigned short)hl << 16);
                        const int c2 = 102 + u;
                        Hst[wb][(c2 >> 5) * TSTR + m * PADR + (c2 & 31)] = hh;
                        C1s[wb][m * 52 + u] = c1;
                    }
                }
            }

            // ---- x writer: stage x(ts+1) into Hst[wb] ----
            if (w == 2 && iloc == 4) {
                const int m = kq;
                const short xh = f2bf(xreg), xl = f2bf(xreg - bf2f(xh));
                Hst[wb][4 * TSTR + m * PADR + 25] = xh;
                Hst[wb][4 * TSTR + m * PADR + 26] = xl;
                Hst[wb][4 * TSTR + m * PADR + 27] = xh;
                xreg = (ts + 2 < SEQT)
                           ? input[(size_t)(r0 + m) * SEQT + ts + 2] : 0.f;
            }
        }

        // ---- z + LSTM3 for step ts-1 (wave 3, parity-separated) ----
        if (w == 3 && ts >= 1) {
            const int s = ts - 1, sp = s & 1;
            const int m = lane >> 4, q = lane & 3;
            float p = 0.f;
#pragma unroll
            for (int ii = 0; ii < 13; ++ii)
                p = fmaf(C1s[sp][m * 52 + q * 13 + ii], w3[ii], p);
            p += __shfl_xor(p, 1);
            p += __shfl_xor(p, 2);
            const int base = lane & ~15;
            const float pi = __shfl(p, base + 0);
            const float pf = __shfl(p, base + 4);
            const float pg = __shfl(p, base + 8);
            const float po = __shfl(p, base + 12);
            const float gi_ = pi + fmaf(whh3_0, h3, b3_0);
            const float gf_ = pf + fmaf(whh3_1, h3, b3_1);
            const float gg_ = pg + fmaf(whh3_2, h3, b3_2);
            const float go_ = po + fmaf(whh3_3, h3, b3_3);
            c3 = sigf(gf_) * c3 + sigf(gi_) * tanhfast(gg_);
            h3 = sigf(go_) * tanhfast(c3);
            if ((lane & 15) == 0)
                Obuf[(s >> 6) & 1][m * 64 + (s & 63)] = c3;
        }
    }

    __syncthreads();
    // tail: steps 1984..1999 (chunk 31, parity 1)
    if (t < 64)
        out[(size_t)(r0 + (t >> 4)) * SEQT + 1984 + (t & 15)] =
            Obuf[1][(t >> 4) * 64 + (t & 15)];
}

extern "C" void kernel_launch(void* const* d_in, const int* in_sizes, int n_in,
                              void* d_out, int out_size, void* d_ws, size_t ws_size,
                              hipStream_t stream) {
    const float* input = (const float*)d_in[0];
    const float* W_ih1 = (const float*)d_in[1];
    const float* W_hh1 = (const float*)d_in[2];
    const float* b_ih1 = (const float*)d_in[3];
    const float* b_hh1 = (const float*)d_in[4];
    const float* W_ih3 = (const float*)d_in[5];
    const float* W_hh3 = (const float*)d_in[6];
    const float* b_ih3 = (const float*)d_in[7];
    const float* b_hh3 = (const float*)d_in[8];
    float* out = (float*)d_out;

    lstm_fused_kernel<<<NBLK, 256, 0, stream>>>(
        input, W_ih1, W_hh1, b_ih1, b_hh1, W_ih3, W_hh3, b_ih3, b_hh3, out);
}

// Round 9
// 2415.858 us; speedup vs baseline: 1.5954x; 1.5954x over previous
//
#include <hip/hip_runtime.h>
#include <hip/hip_bf16.h>

#define SEQT 2000
#define NB   2048
#define H1   51
#define MROW 16
#define NBLK (NB / MROW)   // 128 blocks
#define PADK 328           // shorts per staged row (656 B = 41*16, 16B-aligned)

typedef float f32x4 __attribute__((ext_vector_type(4)));
typedef short s16x8 __attribute__((ext_vector_type(8)));

__device__ __forceinline__ short f2bf(float f) { __hip_bfloat16 b(f); return *(short*)&b; }
__device__ __forceinline__ float bf2f(short s) { __hip_bfloat16 b; *(short*)&b = s; return (float)b; }
__device__ __forceinline__ float rbf(float f) { return bf2f(f2bf(f)); }
__device__ __forceinline__ float sigf(float x) { return 1.f / (1.f + __expf(-x)); }
__device__ __forceinline__ float tanhfast(float x) { return 1.f - 2.f / (__expf(2.f * x) + 1.f); }

// B-side (staged vector) column map, K=320 (10 k-tiles of 32):
//   2u/2u+1 (u<51): h_hi/h_lo      | A: Whh_hi[n][u] (both)
//   102+u   (u<51): h_hi           | A: Whh_lo[n][u]
//   153: x_hi  154: x_lo  155: x_hi| A: Wih_hi, Wih_hi, Wih_lo
//   156: 1.0   157: 1.0            | A: bias_hi, bias_lo
//   158,159: 0
//   160+2u/161+2u (u<51): c1_hi/c1_lo | A(z rows g): W3_hi[g][u] (both)
//   262+u   (u<51): c1_hi             | A(z): W3_lo[g][u]
//   313..319: 0
// Gate rows n' = u*4+g (13 N-tiles, kt 0-4). Z-tile: rows g=0..3 (kt 5-9).
// MFMA A=weights, B=staged vector. C/D: col(lane&15)=m, row(quad*4+reg)=n'
//  -> n'=u*4+g => lane (quad,iloc) holds all 4 gates of (u=nt*4+quad, m=iloc).

__global__ void __launch_bounds__(256)
__attribute__((amdgpu_waves_per_eu(1)))
lstm_fused_kernel(const float* __restrict__ input,
                  const float* __restrict__ W_ih1,
                  const float* __restrict__ W_hh1,
                  const float* __restrict__ b_ih1,
                  const float* __restrict__ b_hh1,
                  const float* __restrict__ W_ih3,
                  const float* __restrict__ W_hh3,
                  const float* __restrict__ b_ih3,
                  const float* __restrict__ b_hh3,
                  float* __restrict__ out) {
    const int t = threadIdx.x;
    const int w = t >> 6;          // wave 0..3
    const int lane = t & 63;
    const int iloc = lane & 15, kq = lane >> 4;
    const int r0 = blockIdx.x * MROW;

    __shared__ short Hst[2][MROW * PADK];   // staged vector rows, parity dbuf
    __shared__ float Obuf[2][MROW * 64];    // c3 chunks

    // tile assignment: w0:{0..3} w1:{4,5}+z w2:{6..9} w3:{10..12}+x
    const int NT = (w == 1) ? 2 : (w == 3) ? 3 : 4;
    const int tb = (w == 0) ? 0 : (w == 1) ? 4 : (w == 2) ? 6 : 10;

    // ---- gate-row weight fragments (A-operand) ----
    s16x8 Wfr[4][5];
#pragma unroll
    for (int i = 0; i < 4; ++i) {
        if (i < NT) {
            const int np = (tb + i) * 16 + iloc;
            const int u = np >> 2, g = np & 3;
            const int n = g * H1 + u;
#pragma unroll
            for (int kt = 0; kt < 5; ++kt) {
                s16x8 bf;
#pragma unroll
                for (int j = 0; j < 8; ++j) {
                    const int k = kt * 32 + kq * 8 + j;
                    float v = 0.f;
                    if (u < H1) {
                        if (k < 102) {
                            v = rbf(W_hh1[n * H1 + (k >> 1)]);
                        } else if (k < 153) {
                            const float wv = W_hh1[n * H1 + (k - 102)];
                            v = wv - rbf(wv);
                        } else if (k == 153 || k == 154) {
                            v = rbf(W_ih1[n]);
                        } else if (k == 155) {
                            const float wv = W_ih1[n];
                            v = wv - rbf(wv);
                        } else if (k == 156) {
                            v = rbf(b_ih1[n] + b_hh1[n]);
                        } else if (k == 157) {
                            const float bv = b_ih1[n] + b_hh1[n];
                            v = bv - rbf(bv);
                        }
                    }
                    bf[j] = f2bf(v);
                }
                Wfr[i][kt] = bf;
            }
        }
    }

    // ---- z-tile A fragments (wave 1): rows g=0..3 = W_ih3 hi/lo ----
    s16x8 Zfr[5];
    if (w == 1) {
        const int g = iloc;
#pragma unroll
        for (int kt = 0; kt < 5; ++kt) {
            s16x8 bf;
#pragma unroll
            for (int j = 0; j < 8; ++j) {
                const int kz = kt * 32 + kq * 8 + j;   // col - 160
                float v = 0.f;
                if (iloc < 4) {
                    if (kz < 102) {
                        v = rbf(W_ih3[g * H1 + (kz >> 1)]);
                    } else if (kz < 153) {
                        const float wv = W_ih3[g * H1 + (kz - 102)];
                        v = wv - rbf(wv);
                    }
                }
                bf[j] = f2bf(v);
            }
            Zfr[kt] = bf;
        }
    }

    const float whh3_0 = W_hh3[0], whh3_1 = W_hh3[1];
    const float whh3_2 = W_hh3[2], whh3_3 = W_hh3[3];
    const float b3_0 = b_ih3[0] + b_hh3[0];
    const float b3_1 = b_ih3[1] + b_hh3[1];
    const float b3_2 = b_ih3[2] + b_hh3[2];
    const float b3_3 = b_ih3[3] + b_hh3[3];

    // ---- LDS init ----
    for (int idx = t; idx < 2 * MROW * PADK; idx += 256)
        ((short*)Hst)[idx] = 0;
    __syncthreads();   // ensure zeros before targeted writes
    if (t < MROW) {
        const int m = t;
#pragma unroll
        for (int p = 0; p < 2; ++p) {
            Hst[p][m * PADK + 156] = (short)0x3F80;   // 1.0
            Hst[p][m * PADK + 157] = (short)0x3F80;
        }
        const float x0 = input[(size_t)(r0 + m) * SEQT];
        const short xh = f2bf(x0), xl = f2bf(x0 - bf2f(xh));
        Hst[1][m * PADK + 153] = xh;   // window 0 reads parity 1
        Hst[1][m * PADK + 154] = xl;
        Hst[1][m * PADK + 155] = xh;
    }
    float xreg = 0.f;
    if (w == 3 && lane < MROW)
        xreg = input[(size_t)(r0 + lane) * SEQT + 1];
    float c1st[4] = {0.f, 0.f, 0.f, 0.f};
    float h3 = 0.f, c3 = 0.f;   // LSTM3 state (wave 1, lanes 0..15)

#pragma unroll 1
    for (int ts = 0; ts <= SEQT; ++ts) {
        __syncthreads();
        const int rb = (ts + 1) & 1, wb = ts & 1;

        // ---- coalesced dump of finished 64-chunk ----
        if (ts >= 65 && (ts & 63) == 1) {
            const int c = (ts >> 6) - 1;
#pragma unroll
            for (int rep = 0; rep < 4; ++rep) {
                const int row = w + 4 * rep;
                out[(size_t)(r0 + row) * SEQT + c * 64 + lane] =
                    Obuf[c & 1][row * 64 + lane];
            }
        }

        if (ts < SEQT) {
            // ---- B-frags: h/x/bias of this step (cols 0..159) ----
            s16x8 hf[5];
#pragma unroll
            for (int kt = 0; kt < 5; ++kt)
                hf[kt] = *(const s16x8*)&Hst[rb][iloc * PADK + kt * 32 + kq * 8];

            // ---- MFMA + dense lane-local epilogue per tile ----
#pragma unroll
            for (int i = 0; i < 4; ++i) {
                if (i < NT) {
                    f32x4 acc = (f32x4){0.f, 0.f, 0.f, 0.f};
#pragma unroll
                    for (int kt = 0; kt < 5; ++kt)
                        acc = __builtin_amdgcn_mfma_f32_16x16x32_bf16(
                            Wfr[i][kt], hf[kt], acc, 0, 0, 0);
                    const int u = (tb + i) * 4 + kq;   // unit
                    const int m = iloc;                // batch row
                    float c1 = c1st[i];
                    c1 = sigf(acc[1]) * c1 + sigf(acc[0]) * tanhfast(acc[2]);
                    c1st[i] = c1;
                    const float h1 = sigf(acc[3]) * tanhfast(c1);
                    if (u < H1) {
                        const short hh = f2bf(h1), hl = f2bf(h1 - bf2f(hh));
                        *(unsigned*)&Hst[wb][m * PADK + 2 * u] =
                            (unsigned)(unsigned short)hh |
                            ((unsigned)(unsigned short)hl << 16);
                        Hst[wb][m * PADK + 102 + u] = hh;
                        const short ch = f2bf(c1), cl = f2bf(c1 - bf2f(ch));
                        *(unsigned*)&Hst[wb][m * PADK + 160 + 2 * u] =
                            (unsigned)(unsigned short)ch |
                            ((unsigned)(unsigned short)cl << 16);
                        Hst[wb][m * PADK + 262 + u] = ch;
                    }
                }
            }

            // ---- x writer: stage x(ts+1) ----
            if (w == 3 && lane < MROW) {
                const int m = lane;
                const short xh = f2bf(xreg), xl = f2bf(xreg - bf2f(xh));
                Hst[wb][m * PADK + 153] = xh;
                Hst[wb][m * PADK + 154] = xl;
                Hst[wb][m * PADK + 155] = xh;
                xreg = (ts + 2 < SEQT)
                           ? input[(size_t)(r0 + m) * SEQT + ts + 2] : 0.f;
            }
        }

        // ---- z + LSTM3 for step ts-1 (wave 1; z-tile MFMA, kt 5..9) ----
        if (w == 1 && ts >= 1) {
            s16x8 zf[5];
#pragma unroll
            for (int kt = 0; kt < 5; ++kt)
                zf[kt] = *(const s16x8*)
                    &Hst[rb][iloc * PADK + 160 + kt * 32 + kq * 8];
            f32x4 zacc = (f32x4){0.f, 0.f, 0.f, 0.f};
#pragma unroll
            for (int kt = 0; kt < 5; ++kt)
                zacc = __builtin_amdgcn_mfma_f32_16x16x32_bf16(
                    Zfr[kt], zf[kt], zacc, 0, 0, 0);
            if (lane < MROW) {   // lanes 0..15 hold rows 0..3 = gates in regs
                const int m = lane, s = ts - 1;
                const float gi = zacc[0] + fmaf(whh3_0, h3, b3_0);
                const float gf = zacc[1] + fmaf(whh3_1, h3, b3_1);
                const float gg = zacc[2] + fmaf(whh3_2, h3, b3_2);
                const float go = zacc[3] + fmaf(whh3_3, h3, b3_3);
                c3 = sigf(gf) * c3 + sigf(gi) * tanhfast(gg);
                h3 = sigf(go) * tanhfast(c3);
                Obuf[(s >> 6) & 1][m * 64 + (s & 63)] = c3;
            }
        }
    }

    __syncthreads();
    // tail: steps 1984..1999 (chunk 31, parity 1)
    {
        const int row = t >> 4, pos = t & 15;
        out[(size_t)(r0 + row) * SEQT + 1984 + pos] = Obuf[1][row * 64 + pos];
    }
}

extern "C" void kernel_launch(void* const* d_in, const int* in_sizes, int n_in,
                              void* d_out, int out_size, void* d_ws, size_t ws_size,
                              hipStream_t stream) {
    const float* input = (const float*)d_in[0];
    const float* W_ih1 = (const float*)d_in[1];
    const float* W_hh1 = (const float*)d_in[2];
    const float* b_ih1 = (const float*)d_in[3];
    const float* b_hh1 = (const float*)d_in[4];
    const float* W_ih3 = (const float*)d_in[5];
    const float* W_hh3 = (const float*)d_in[6];
    const float* b_ih3 = (const float*)d_in[7];
    const float* b_hh3 = (const float*)d_in[8];
    float* out = (float*)d_out;

    lstm_fused_kernel<<<NBLK, 256, 0, stream>>>(
        input, W_ih1, W_hh1, b_ih1, b_hh1, W_ih3, W_hh3, b_ih3, b_hh3, out);
}